// Round 8
// baseline (159.577 us; speedup 1.0000x reference)
//
#include <hip/hip_runtime.h>
#include <hip/hip_cooperative_groups.h>
#include <stdint.h>

namespace cg = cooperative_groups;

#define NUM_BBOX    2
#define NUM_CLASSES 20
#define NUM_GRID    7
#define BATCH       64
#define NCELL  (BATCH * NUM_GRID * NUM_GRID)   // 3136
#define NCAND  (NCELL * NUM_BBOX)              // 6272
#define NGROUP (BATCH * NUM_CLASSES)           // 1280
#define MAXG   98
#define NBLK   784                             // 98 i-groups x 8 j-tiles
#define JTILE  (NCAND / 8)                     // 784

// ---- workspace layout (bytes) ----
#define WS_SCORE     0         // f32[6272]            25088
#define WS_CELLBOX   25088     // f32[3136*4]          50176
#define WS_CELLLAB   75264     // f32[3136]            12544
#define WS_KEYS      87808     // u64[6272]            50176
#define WS_KEEP      137984    // f32[6272]            25088
#define WS_RANK      163072    // u32[6272]            25088

// monotone float -> sortable u32 (ascending float == ascending u32)
__device__ __forceinline__ unsigned fkey(float f) {
    unsigned u = __float_as_uint(f);
    return (u & 0x80000000u) ? ~u : (u | 0x80000000u);
}

__device__ __forceinline__ float iou_rn(float4 a, float4 b) {
    float xx1 = fmaxf(a.x, b.x), yy1 = fmaxf(a.y, b.y);
    float xx2 = fminf(a.z, b.z), yy2 = fminf(a.w, b.w);
    float w = fmaxf(__fsub_rn(xx2, xx1), 0.0f);
    float h = fmaxf(__fsub_rn(yy2, yy1), 0.0f);
    float inter = __fmul_rn(w, h);
    float aa = __fmul_rn(__fsub_rn(a.z, a.x), __fsub_rn(a.w, a.y));
    float ab = __fmul_rn(__fsub_rn(b.z, b.x), __fsub_rn(b.w, b.y));
    float denom = __fadd_rn(__fsub_rn(__fadd_rn(aa, ab), inter), 1e-9f);
    return __fdiv_rn(inter, denom);
}

// Single cooperative kernel: 784 blocks x 64 lanes.
// P1 decode+zero -> sync -> P2 rank-partials + group NMS -> sync -> P3 scatter.
// Each phase keeps the exact geometry of the proven R4 kernels.
__global__ void __launch_bounds__(64) k_fused(
        const float* __restrict__ in,
        float* __restrict__ score,
        float* __restrict__ cellBox,
        float* __restrict__ cellLabel,
        unsigned long long* __restrict__ keys,
        float* __restrict__ keepOrig,
        unsigned* __restrict__ rank,
        float* __restrict__ out) {
    cg::grid_group grid = cg::this_grid();
    __shared__ unsigned long long mkey[MAXG];
    __shared__ unsigned long long skey[MAXG];
    const int bid  = (int)blockIdx.x;
    const int lane = (int)threadIdx.x;

    // ---------- phase 1: decode (blocks 0-48) + zero rank/keep (blocks 0-97) ----------
    if (bid < 98) {
        int idx = bid * 64 + lane;                 // covers 6272 exactly
        rank[idx] = 0u;
        keepOrig[idx] = 0.0f;
    }
    if (bid < 49) {
        int cell = bid * 64 + lane;                // covers 3136 exactly
        const float* p = in + cell * (NUM_BBOX * (5 + NUM_CLASSES));
        int rc = cell % (NUM_GRID * NUM_GRID);
        int r = rc / NUM_GRID, c = rc % NUM_GRID;

        float sc[NUM_BBOX];
        for (int bb = 0; bb < NUM_BBOX; ++bb) {
            const float* q = p + bb * 25;
            float conf = q[4];
            float m = __fmul_rn(q[5], conf);
            for (int k = 1; k < NUM_CLASSES; ++k)
                m = fmaxf(m, __fmul_rn(q[5 + k], conf));
            sc[bb] = m;
        }
        int best = (sc[1] > sc[0]) ? 1 : 0;        // first-occurrence argmax
        const float* q = p + best * 25;

        int lab = 0; float bv = q[5];
        for (int k = 1; k < NUM_CLASSES; ++k)
            if (q[5 + k] > bv) { bv = q[5 + k]; lab = k; }

        float x  = __fdiv_rn(__fadd_rn(q[0], (float)r), 7.0f);
        float y  = __fdiv_rn(__fadd_rn(q[1], (float)c), 7.0f);
        float hw = __fmul_rn(q[2], 0.5f);
        float hh = __fmul_rn(q[3], 0.5f);
        cellBox[cell * 4 + 0] = __fsub_rn(x, hw);
        cellBox[cell * 4 + 1] = __fsub_rn(y, hh);
        cellBox[cell * 4 + 2] = __fadd_rn(x, hw);
        cellBox[cell * 4 + 3] = __fadd_rn(y, hh);
        cellLabel[cell] = (float)(lab + 1);

        for (int bb = 0; bb < NUM_BBOX; ++bb) {
            int idx = cell * NUM_BBOX + bb;
            score[idx] = sc[bb];
            bool valid = sc[bb] > 0.5f;
            float kf = valid ? -sc[bb] : __builtin_inff();
            keys[idx] = ((unsigned long long)fkey(kf) << 32) | (unsigned)idx;
        }
    }

    grid.sync();

    // ---------- phase 2a: rank partial (R4 k_rank geometry) ----------
    {
        int ib = bid >> 3;                         // 0..97
        int jt = bid & 7;                          // 0..7
        int i  = ib * 64 + lane;
        unsigned long long my = keys[i];
        const unsigned long long* kj = keys + jt * JTILE;
        unsigned r = 0;
        #pragma unroll 16
        for (int j = 0; j < JTILE; ++j)
            r += (kj[j] < my) ? 1u : 0u;
        atomicAdd(&rank[i], r);
    }

    // ---------- phase 2b: per-group NMS (R4 k_nms body), groups bid, bid+784 ----------
    for (int g = bid; g < NGROUP; g += NBLK) {
        int b = g / NUM_CLASSES;
        float lab = (float)(g % NUM_CLASSES + 1);
        int base = b * MAXG;

        unsigned long long key0 = keys[base + lane];
        bool v0 = ((unsigned)(key0 >> 32) < 0x80000000u) &&
                  (cellLabel[(base + lane) >> 1] == lab);
        unsigned long long key1 = 0; bool v1 = false;
        if (lane + 64 < MAXG) {
            key1 = keys[base + lane + 64];
            v1 = ((unsigned)(key1 >> 32) < 0x80000000u) &&
                 (cellLabel[(base + lane + 64) >> 1] == lab);
        }

        unsigned long long b0 = __ballot(v0);
        unsigned long long b1 = __ballot(v1);
        int n0 = __popcll(b0);
        int n  = n0 + __popcll(b1);
        __syncthreads();                           // WAR guard across g-iterations
        if (n > 0) {
            unsigned long long below = (1ull << lane) - 1ull;
            if (v0) mkey[__popcll(b0 & below)] = key0;
            if (v1) mkey[n0 + __popcll(b1 & below)] = key1;
            __syncthreads();

            for (int s = 0; s < 2; ++s) {
                int j = lane + s * 64;
                if (j < n) {
                    unsigned long long kj = mkey[j];
                    int rr = 0;
                    for (int i2 = 0; i2 < n; ++i2) rr += (mkey[i2] < kj) ? 1 : 0;
                    skey[rr] = kj;                 // rank-by-count == stable sort
                }
            }
            __syncthreads();

            float4 box0 = make_float4(0.f, 0.f, 0.f, 0.f), box1 = box0;
            int idx0 = 0, idx1 = 0, keep0 = 0, keep1 = 0;
            if (lane < n) {
                idx0 = (int)(unsigned)skey[lane];
                box0 = *(const float4*)(cellBox + (idx0 >> 1) * 4);
                keep0 = 1;
            }
            if (lane + 64 < n) {
                idx1 = (int)(unsigned)skey[lane + 64];
                box1 = *(const float4*)(cellBox + (idx1 >> 1) * 4);
                keep1 = 1;
            }
            for (int i = 0; i < n; ++i) {
                int srcl = i & 63;
                int ki = __shfl((i < 64) ? keep0 : keep1, srcl);
                if (ki) {
                    float4 s4 = (i < 64) ? box0 : box1;
                    float4 bi;
                    bi.x = __shfl(s4.x, srcl);
                    bi.y = __shfl(s4.y, srcl);
                    bi.z = __shfl(s4.z, srcl);
                    bi.w = __shfl(s4.w, srcl);
                    if (keep0 && lane > i)      { if (iou_rn(bi, box0) > 0.3f) keep0 = 0; }
                    if (keep1 && lane + 64 > i) { if (iou_rn(bi, box1) > 0.3f) keep1 = 0; }
                }
            }
            if (keep0) keepOrig[idx0] = 1.0f;
            if (keep1) keepOrig[idx1] = 1.0f;
        }
    }

    grid.sync();

    // ---------- phase 3: scatter (R4 k_scatter geometry, blocks 0-97) ----------
    if (bid < 98) {
        int i = bid * 64 + lane;
        unsigned rr = rank[i];
        int cell = i >> 1;
        out[rr] = (float)(i / 98);                 // batch id
        float4 bx = *(const float4*)(cellBox + cell * 4);
        *(float4*)(out + NCAND + rr * 4) = bx;
        out[NCAND * 5 + rr] = cellLabel[cell];
        out[NCAND * 6 + rr] = score[i];
        out[NCAND * 7 + rr] = keepOrig[i];
    }
}

extern "C" void kernel_launch(void* const* d_in, const int* in_sizes, int n_in,
                              void* d_out, int out_size, void* d_ws, size_t ws_size,
                              hipStream_t stream) {
    const float*        in        = (const float*)d_in[0];
    char* ws = (char*)d_ws;
    float*              score     = (float*)(ws + WS_SCORE);
    float*              cellBox   = (float*)(ws + WS_CELLBOX);
    float*              cellLabel = (float*)(ws + WS_CELLLAB);
    unsigned long long* keys      = (unsigned long long*)(ws + WS_KEYS);
    float*              keepOrig  = (float*)(ws + WS_KEEP);
    unsigned*           rank      = (unsigned*)(ws + WS_RANK);
    float*              out       = (float*)d_out;

    void* args[] = {(void*)&in, (void*)&score, (void*)&cellBox, (void*)&cellLabel,
                    (void*)&keys, (void*)&keepOrig, (void*)&rank, (void*)&out};
    hipLaunchCooperativeKernel((void*)k_fused, dim3(NBLK), dim3(64), args, 0, stream);
}

// Round 9
// 29.184 us; speedup vs baseline: 5.4680x; 5.4680x over previous
//
#include <hip/hip_runtime.h>
#include <stdint.h>

#define NUM_BBOX    2
#define NUM_CLASSES 20
#define NUM_GRID    7
#define BATCH       64
#define NCELL  (BATCH * NUM_GRID * NUM_GRID)   // 3136
#define NCAND  (NCELL * NUM_BBOX)              // 6272
#define NGROUP (BATCH * NUM_CLASSES)           // 1280
#define MAXG   98
#define NRANKB 784                             // 98 i-groups x 8 j-tiles
#define JTILE  (NCAND / 8)                     // 784

// ---- workspace layout (bytes) ----
#define WS_SCORE     0         // f32[6272]            25088
#define WS_CELLBOX   25088     // f32[3136*4]          50176
#define WS_CELLLAB   75264     // f32[3136]            12544
#define WS_KEYS      87808     // u64[6272]            50176
#define WS_KEEP      137984    // f32[6272]            25088
#define WS_RANK      163072    // u32[6272]            25088

// monotone float -> sortable u32 (ascending float == ascending u32)
__device__ __forceinline__ unsigned fkey(float f) {
    unsigned u = __float_as_uint(f);
    return (u & 0x80000000u) ? ~u : (u | 0x80000000u);
}

__device__ __forceinline__ float iou_rn(float4 a, float4 b) {
    float xx1 = fmaxf(a.x, b.x), yy1 = fmaxf(a.y, b.y);
    float xx2 = fminf(a.z, b.z), yy2 = fminf(a.w, b.w);
    float w = fmaxf(__fsub_rn(xx2, xx1), 0.0f);
    float h = fmaxf(__fsub_rn(yy2, yy1), 0.0f);
    float inter = __fmul_rn(w, h);
    float aa = __fmul_rn(__fsub_rn(a.z, a.x), __fsub_rn(a.w, a.y));
    float ab = __fmul_rn(__fsub_rn(b.z, b.x), __fsub_rn(b.w, b.y));
    float denom = __fadd_rn(__fsub_rn(__fadd_rn(aa, ab), inter), 1e-9f);
    return __fdiv_rn(inter, denom);
}

__global__ void k_decode(const float* __restrict__ in,
                         float* __restrict__ score,
                         float* __restrict__ cellBox,
                         float* __restrict__ cellLabel,
                         unsigned long long* __restrict__ keys,
                         float* __restrict__ keepOrig,
                         unsigned* __restrict__ rank) {
    int cell = blockIdx.x * blockDim.x + threadIdx.x;
    if (cell >= NCELL) return;
    const float* p = in + cell * (NUM_BBOX * (5 + NUM_CLASSES));
    int rc = cell % (NUM_GRID * NUM_GRID);
    int r = rc / NUM_GRID, c = rc % NUM_GRID;

    // per-bbox score = max_cls (prob*conf)  -- mul then max, matching reference
    float sc[NUM_BBOX];
    for (int bb = 0; bb < NUM_BBOX; ++bb) {
        const float* q = p + bb * 25;
        float conf = q[4];
        float m = __fmul_rn(q[5], conf);
        for (int k = 1; k < NUM_CLASSES; ++k)
            m = fmaxf(m, __fmul_rn(q[5 + k], conf));
        sc[bb] = m;
    }
    int best = (sc[1] > sc[0]) ? 1 : 0;   // first-occurrence argmax over 2
    const float* q = p + best * 25;

    // label = argmax over classes (first occurrence) + 1
    int lab = 0; float bv = q[5];
    for (int k = 1; k < NUM_CLASSES; ++k)
        if (q[5 + k] > bv) { bv = q[5 + k]; lab = k; }

    // box: x uses row index, y uses col index (as in reference)
    float x  = __fdiv_rn(__fadd_rn(q[0], (float)r), 7.0f);
    float y  = __fdiv_rn(__fadd_rn(q[1], (float)c), 7.0f);
    float hw = __fmul_rn(q[2], 0.5f);
    float hh = __fmul_rn(q[3], 0.5f);
    float x1 = __fsub_rn(x, hw), y1 = __fsub_rn(y, hh);
    float x2 = __fadd_rn(x, hw), y2 = __fadd_rn(y, hh);

    cellBox[cell * 4 + 0] = x1;
    cellBox[cell * 4 + 1] = y1;
    cellBox[cell * 4 + 2] = x2;
    cellBox[cell * 4 + 3] = y2;
    cellLabel[cell] = (float)(lab + 1);

    for (int bb = 0; bb < NUM_BBOX; ++bb) {
        int idx = cell * NUM_BBOX + bb;
        score[idx] = sc[bb];
        keepOrig[idx] = 0.0f;
        rank[idx] = 0u;
        bool valid = sc[bb] > 0.5f;
        float kf = valid ? -sc[bb] : __builtin_inff();
        keys[idx] = ((unsigned long long)fkey(kf) << 32) | (unsigned)idx;
    }
}

// Union grid: blocks [0,784) = rank partials (R4 k_rank verbatim);
// blocks [784, 784+1280) = per-group NMS (R4 k_nms verbatim).
// Both branches depend only on decode outputs and are mutually independent.
__global__ void __launch_bounds__(64) k_nms_rank(
        const unsigned long long* __restrict__ keys,
        const float* __restrict__ cellLabel,
        const float* __restrict__ cellBox,
        float* __restrict__ keepOrig,
        unsigned* __restrict__ rank) {
    __shared__ unsigned long long mkey[MAXG];
    __shared__ unsigned long long skey[MAXG];
    const int bid  = (int)blockIdx.x;
    const int lane = (int)threadIdx.x;

    if (bid < NRANKB) {
        // ---- rank partial: rank[i] += #{ j in tile : keys[j] < keys[i] } ----
        int ib = bid >> 3;                     // 0..97
        int jt = bid & 7;                      // 0..7
        int i  = ib * 64 + lane;
        unsigned long long my = keys[i];
        const unsigned long long* kj = keys + jt * JTILE;
        unsigned r = 0;
        #pragma unroll 8
        for (int j = 0; j < JTILE; ++j)
            r += (kj[j] < my) ? 1u : 0u;
        atomicAdd(&rank[i], r);
        return;
    }

    // ---- per-(batch,label) NMS, single wave ----
    int g = bid - NRANKB;
    int b = g / NUM_CLASSES;
    float lab = (float)(g % NUM_CLASSES + 1);
    int base = b * MAXG;

    unsigned long long key0 = keys[base + lane];
    bool v0 = ((unsigned)(key0 >> 32) < 0x80000000u) &&
              (cellLabel[(base + lane) >> 1] == lab);
    unsigned long long key1 = 0; bool v1 = false;
    if (lane + 64 < MAXG) {
        key1 = keys[base + lane + 64];
        v1 = ((unsigned)(key1 >> 32) < 0x80000000u) &&
             (cellLabel[(base + lane + 64) >> 1] == lab);
    }

    unsigned long long b0 = __ballot(v0);
    unsigned long long b1 = __ballot(v1);
    int n0 = __popcll(b0);
    int n  = n0 + __popcll(b1);
    if (n == 0) return;

    unsigned long long below = (1ull << lane) - 1ull;
    if (v0) mkey[__popcll(b0 & below)] = key0;
    if (v1) mkey[n0 + __popcll(b1 & below)] = key1;
    __syncthreads();

    // sorted position = # members with smaller key (stable, keys unique)
    for (int s = 0; s < 2; ++s) {
        int j = lane + s * 64;
        if (j < n) {
            unsigned long long kj = mkey[j];
            int r = 0;
            for (int i = 0; i < n; ++i) r += (mkey[i] < kj) ? 1 : 0;
            skey[r] = kj;
        }
    }
    __syncthreads();

    float4 box0 = make_float4(0.f, 0.f, 0.f, 0.f), box1 = box0;
    int idx0 = 0, idx1 = 0, keep0 = 0, keep1 = 0;
    if (lane < n) {
        idx0 = (int)(unsigned)skey[lane];
        box0 = *(const float4*)(cellBox + (idx0 >> 1) * 4);
        keep0 = 1;
    }
    if (lane + 64 < n) {
        idx1 = (int)(unsigned)skey[lane + 64];
        box1 = *(const float4*)(cellBox + (idx1 >> 1) * 4);
        keep1 = 1;
    }

    for (int i = 0; i < n; ++i) {
        int srcl = i & 63;
        int ki = __shfl((i < 64) ? keep0 : keep1, srcl);
        if (ki) {
            float4 src = (i < 64) ? box0 : box1;
            float4 bi;
            bi.x = __shfl(src.x, srcl);
            bi.y = __shfl(src.y, srcl);
            bi.z = __shfl(src.z, srcl);
            bi.w = __shfl(src.w, srcl);
            if (keep0 && lane > i) {
                if (iou_rn(bi, box0) > 0.3f) keep0 = 0;
            }
            if (keep1 && lane + 64 > i) {
                if (iou_rn(bi, box1) > 0.3f) keep1 = 0;
            }
        }
    }
    if (keep0) keepOrig[idx0] = 1.0f;
    if (keep1) keepOrig[idx1] = 1.0f;
}

// write source element i to its sorted position rank[i]
__global__ void __launch_bounds__(64) k_scatter(
        const unsigned* __restrict__ rank,
        const float* __restrict__ score,
        const float* __restrict__ cellBox,
        const float* __restrict__ cellLabel,
        const float* __restrict__ keepOrig,
        float* __restrict__ out) {
    int i = blockIdx.x * 64 + (int)threadIdx.x;
    unsigned r = rank[i];
    int cell = i >> 1;
    // idx = b*98 + (rc*2+bb) with rc*2+bb < 98  ->  i/98 == batch id
    out[r] = (float)(i / 98);
    float4 bx = *(const float4*)(cellBox + cell * 4);
    *(float4*)(out + NCAND + r * 4) = bx;
    out[NCAND * 5 + r] = cellLabel[cell];
    out[NCAND * 6 + r] = score[i];
    out[NCAND * 7 + r] = keepOrig[i];
}

extern "C" void kernel_launch(void* const* d_in, const int* in_sizes, int n_in,
                              void* d_out, int out_size, void* d_ws, size_t ws_size,
                              hipStream_t stream) {
    const float* in = (const float*)d_in[0];
    char* ws = (char*)d_ws;
    float*              score     = (float*)(ws + WS_SCORE);
    float*              cellBox   = (float*)(ws + WS_CELLBOX);
    float*              cellLabel = (float*)(ws + WS_CELLLAB);
    unsigned long long* keys      = (unsigned long long*)(ws + WS_KEYS);
    float*              keepOrig  = (float*)(ws + WS_KEEP);
    unsigned*           rank      = (unsigned*)(ws + WS_RANK);
    float* out = (float*)d_out;

    k_decode<<<(NCELL + 63) / 64, 64, 0, stream>>>(in, score, cellBox, cellLabel,
                                                   keys, keepOrig, rank);
    k_nms_rank<<<NRANKB + NGROUP, 64, 0, stream>>>(keys, cellLabel, cellBox,
                                                   keepOrig, rank);
    k_scatter<<<NCAND / 64, 64, 0, stream>>>(rank, score, cellBox, cellLabel,
                                             keepOrig, out);
}

// Round 10
// 23.408 us; speedup vs baseline: 6.8172x; 1.2467x over previous
//
#include <hip/hip_runtime.h>
#include <stdint.h>

#define NUM_BBOX    2
#define NUM_CLASSES 20
#define NUM_GRID    7
#define BATCH       64
#define NCELL  (BATCH * NUM_GRID * NUM_GRID)   // 3136
#define NCAND  (NCELL * NUM_BBOX)              // 6272
#define NGROUP (BATCH * NUM_CLASSES)           // 1280
#define MAXG   98
#define CPB    49                              // cells per batch
#define KPB    98                              // candidates per batch
#define NJT    8
#define JTILE  (NCAND / NJT)                   // 784 candidates per j-tile
#define JCELLS (JTILE / 2)                     // 392 cells per j-tile

#define NDECB   49                             // decode blocks (49*64 = 3136 cells)
#define B_RANK0 NDECB                          // rank blocks [49, 833)
#define B_NMS0  (NDECB + 784)                  // nms blocks  [833, 2113)
#define NBLK_K1 (NDECB + 784 + NGROUP)         // 2113

// ---- workspace layout (bytes) ----
#define WS_SCORE     0         // f32[6272]            25088
#define WS_CELLBOX   25088     // f32[3136*4]          50176
#define WS_CELLLAB   75264     // f32[3136]            12544
#define WS_KEEP      87808     // f32[6272]            25088
#define WS_RANKP     112896    // u32[8*6272]         200704

// monotone float -> sortable u32 (ascending float == ascending u32)
__device__ __forceinline__ unsigned fkey(float f) {
    unsigned u = __float_as_uint(f);
    return (u & 0x80000000u) ? ~u : (u | 0x80000000u);
}

// score of one bbox slice q[0..25): conf * max cls prob, mul-then-max chain
__device__ __forceinline__ float cand_score(const float* q) {
    float conf = q[4];
    float m = __fmul_rn(q[5], conf);
    #pragma unroll
    for (int k = 1; k < NUM_CLASSES; ++k)
        m = fmaxf(m, __fmul_rn(q[5 + k], conf));
    return m;
}

__device__ __forceinline__ float iou_rn(float4 a, float4 b) {
    float xx1 = fmaxf(a.x, b.x), yy1 = fmaxf(a.y, b.y);
    float xx2 = fminf(a.z, b.z), yy2 = fminf(a.w, b.w);
    float w = fmaxf(__fsub_rn(xx2, xx1), 0.0f);
    float h = fmaxf(__fsub_rn(yy2, yy1), 0.0f);
    float inter = __fmul_rn(w, h);
    float aa = __fmul_rn(__fsub_rn(a.z, a.x), __fsub_rn(a.w, a.y));
    float ab = __fmul_rn(__fsub_rn(b.z, b.x), __fsub_rn(b.w, b.y));
    float denom = __fadd_rn(__fsub_rn(__fadd_rn(aa, ab), inter), 1e-9f);
    return __fdiv_rn(inter, denom);
}

// Union kernel: 2113 independent blocks x 64 lanes.
//  [0,49):    decode  -> score, cellBox, cellLabel   (sole writer)
//  [49,833):  rank    -> rankPart[jt][i]             (sole writer, plain stores;
//             keys for i-tile and j-tile recomputed from input)
//  [833,2113):nms     -> keepOrig                    (sole writer; R7-proven
//             redundant per-batch decode, disjoint-complete keep ownership)
__global__ void __launch_bounds__(64) k_main(
        const float* __restrict__ in,
        float* __restrict__ score,
        float* __restrict__ cellBox,
        float* __restrict__ cellLabel,
        float* __restrict__ keepOrig,
        unsigned* __restrict__ rankPart) {
    __shared__ union SMem {
        unsigned long long jkey[JTILE];            // rank branch (6272 B)
        struct {                                   // nms branch (~13.5 KB)
            float2 raw2[1225];
            unsigned long long lkey[KPB];
            float4 lbox[CPB];
            int    llab[CPB];
            float  lkeep[KPB];
            unsigned long long mkey[KPB];
            unsigned long long skey[KPB];
        } nms;
    } sm;

    const int bid  = (int)blockIdx.x;
    const int lane = (int)threadIdx.x;

    // ---------------- decode blocks ----------------
    if (bid < NDECB) {
        int cell = bid * 64 + lane;                // covers 3136 exactly
        const float* p = in + cell * 50;
        float s0 = cand_score(p);
        float s1 = cand_score(p + 25);
        int best = (s1 > s0) ? 1 : 0;              // first-occurrence argmax
        const float* q = p + best * 25;

        int lab = 0; float bv = q[5];
        #pragma unroll
        for (int k = 1; k < NUM_CLASSES; ++k)
            if (q[5 + k] > bv) { bv = q[5 + k]; lab = k; }

        int rc = cell % (NUM_GRID * NUM_GRID);
        int r = rc / NUM_GRID, c = rc % NUM_GRID;
        float x  = __fdiv_rn(__fadd_rn(q[0], (float)r), 7.0f);
        float y  = __fdiv_rn(__fadd_rn(q[1], (float)c), 7.0f);
        float hw = __fmul_rn(q[2], 0.5f);
        float hh = __fmul_rn(q[3], 0.5f);
        *(float4*)(cellBox + cell * 4) =
            make_float4(__fsub_rn(x, hw), __fsub_rn(y, hh),
                        __fadd_rn(x, hw), __fadd_rn(y, hh));
        cellLabel[cell] = (float)(lab + 1);
        score[cell * 2 + 0] = s0;
        score[cell * 2 + 1] = s1;
        return;
    }

    // ---------------- rank blocks ----------------
    if (bid < B_NMS0) {
        int rb = bid - B_RANK0;
        int ib = rb >> 3;                          // 0..97
        int jt = rb & 7;                           // 0..7

        // cooperative keys-only decode of the j-tile into LDS
        for (int cl = lane; cl < JCELLS; cl += 64) {
            int cell = jt * JCELLS + cl;
            const float* p = in + cell * 50;
            #pragma unroll
            for (int bb = 0; bb < 2; ++bb) {
                float s = cand_score(p + bb * 25);
                bool valid = s > 0.5f;
                float kf = valid ? -s : __builtin_inff();
                sm.jkey[cl * 2 + bb] =
                    ((unsigned long long)fkey(kf) << 32) | (unsigned)(cell * 2 + bb);
            }
        }
        // own key
        int i = ib * 64 + lane;
        unsigned long long my;
        {
            const float* q = in + (i >> 1) * 50 + (i & 1) * 25;
            float s = cand_score(q);
            bool valid = s > 0.5f;
            float kf = valid ? -s : __builtin_inff();
            my = ((unsigned long long)fkey(kf) << 32) | (unsigned)i;
        }
        __syncthreads();

        unsigned r = 0;
        #pragma unroll 8
        for (int j = 0; j < JTILE; ++j)
            r += (sm.jkey[j] < my) ? 1u : 0u;
        rankPart[jt * NCAND + i] = r;              // plain store, sole writer
        return;
    }

    // ---------------- nms blocks (R7-proven body) ----------------
    int g = bid - B_NMS0;
    int b = g / NUM_CLASSES;
    int L = g % NUM_CLASSES + 1;
    int base = b * KPB;

    const float2* src = (const float2*)(in + b * (CPB * 50));
    for (int t = lane; t < 1225; t += 64) sm.nms.raw2[t] = src[t];
    sm.nms.lkeep[lane] = 0.0f;
    if (lane + 64 < KPB) sm.nms.lkeep[lane + 64] = 0.0f;
    __syncthreads();

    if (lane < CPB) {
        const float* p = (const float*)sm.nms.raw2 + lane * 50;
        float s0 = cand_score(p);
        float s1 = cand_score(p + 25);
        int best = (s1 > s0) ? 1 : 0;
        const float* q = p + best * 25;

        int lab = 0; float bv = q[5];
        #pragma unroll
        for (int k = 1; k < NUM_CLASSES; ++k)
            if (q[5 + k] > bv) { bv = q[5 + k]; lab = k; }

        int r = lane / NUM_GRID, c = lane % NUM_GRID;
        float x  = __fdiv_rn(__fadd_rn(q[0], (float)r), 7.0f);
        float y  = __fdiv_rn(__fadd_rn(q[1], (float)c), 7.0f);
        float hw = __fmul_rn(q[2], 0.5f);
        float hh = __fmul_rn(q[3], 0.5f);
        sm.nms.lbox[lane] = make_float4(__fsub_rn(x, hw), __fsub_rn(y, hh),
                                        __fadd_rn(x, hw), __fadd_rn(y, hh));
        sm.nms.llab[lane] = lab + 1;
        float ss0 = s0, ss1 = s1;
        {
            bool valid = ss0 > 0.5f;
            float kf = valid ? -ss0 : __builtin_inff();
            sm.nms.lkey[lane * 2 + 0] =
                ((unsigned long long)fkey(kf) << 32) | (unsigned)(base + lane * 2 + 0);
        }
        {
            bool valid = ss1 > 0.5f;
            float kf = valid ? -ss1 : __builtin_inff();
            sm.nms.lkey[lane * 2 + 1] =
                ((unsigned long long)fkey(kf) << 32) | (unsigned)(base + lane * 2 + 1);
        }
    }
    __syncthreads();

    unsigned long long key0 = sm.nms.lkey[lane];
    int lab0 = sm.nms.llab[lane >> 1];
    bool v0 = ((unsigned)(key0 >> 32) < 0x80000000u) && (lab0 == L);
    unsigned long long key1 = 0; bool v1 = false; int lab1 = -1;
    if (lane + 64 < KPB) {
        key1 = sm.nms.lkey[lane + 64];
        lab1 = sm.nms.llab[(lane + 64) >> 1];
        v1 = ((unsigned)(key1 >> 32) < 0x80000000u) && (lab1 == L);
    }
    unsigned long long b0 = __ballot(v0);
    unsigned long long b1 = __ballot(v1);
    int n0 = __popcll(b0);
    int n  = n0 + __popcll(b1);
    unsigned long long below = (1ull << lane) - 1ull;
    if (v0) sm.nms.mkey[__popcll(b0 & below)] = key0;
    if (v1) sm.nms.mkey[n0 + __popcll(b1 & below)] = key1;
    __syncthreads();

    if (n > 0) {
        for (int s = 0; s < 2; ++s) {
            int j = lane + s * 64;
            if (j < n) {
                unsigned long long kj = sm.nms.mkey[j];
                int rr = 0;
                for (int i2 = 0; i2 < n; ++i2) rr += (sm.nms.mkey[i2] < kj) ? 1 : 0;
                sm.nms.skey[rr] = kj;              // rank-by-count == stable sort
            }
        }
    }
    __syncthreads();

    if (n > 0) {
        float4 box0 = make_float4(0.f, 0.f, 0.f, 0.f), box1 = box0;
        int t0 = 0, t1 = 0, keep0 = 0, keep1 = 0;
        if (lane < n) {
            t0 = (int)(unsigned)sm.nms.skey[lane] - base;
            box0 = sm.nms.lbox[t0 >> 1];
            keep0 = 1;
        }
        if (lane + 64 < n) {
            t1 = (int)(unsigned)sm.nms.skey[lane + 64] - base;
            box1 = sm.nms.lbox[t1 >> 1];
            keep1 = 1;
        }
        for (int i = 0; i < n; ++i) {
            int srcl = i & 63;
            int ki = __shfl((i < 64) ? keep0 : keep1, srcl);
            if (ki) {
                float4 s4 = (i < 64) ? box0 : box1;
                float4 bi;
                bi.x = __shfl(s4.x, srcl);
                bi.y = __shfl(s4.y, srcl);
                bi.z = __shfl(s4.z, srcl);
                bi.w = __shfl(s4.w, srcl);
                if (keep0 && lane > i)      { if (iou_rn(bi, box0) > 0.3f) keep0 = 0; }
                if (keep1 && lane + 64 > i) { if (iou_rn(bi, box1) > 0.3f) keep1 = 0; }
            }
        }
        if (keep0) sm.nms.lkeep[t0] = 1.0f;
        if (keep1) sm.nms.lkeep[t1] = 1.0f;
    }
    __syncthreads();

    // keep for exactly this block's label (disjoint-complete across blocks)
    if (lab0 == L) keepOrig[base + lane] = sm.nms.lkeep[lane];
    if (lane + 64 < KPB && lab1 == L) keepOrig[base + lane + 64] = sm.nms.lkeep[lane + 64];
}

// 98 blocks x 64: sum the 8 rank partials, scatter all outputs.
__global__ void __launch_bounds__(64) k_scatter(
        const unsigned* __restrict__ rankPart,
        const float* __restrict__ score,
        const float* __restrict__ cellBox,
        const float* __restrict__ cellLabel,
        const float* __restrict__ keepOrig,
        float* __restrict__ out) {
    int i = blockIdx.x * 64 + (int)threadIdx.x;
    unsigned r = 0;
    #pragma unroll
    for (int jt = 0; jt < NJT; ++jt) r += rankPart[jt * NCAND + i];
    int cell = i >> 1;
    out[r] = (float)(i / 98);                      // batch id
    float4 bx = *(const float4*)(cellBox + cell * 4);
    *(float4*)(out + NCAND + r * 4) = bx;
    out[NCAND * 5 + r] = cellLabel[cell];
    out[NCAND * 6 + r] = score[i];
    out[NCAND * 7 + r] = keepOrig[i];
}

extern "C" void kernel_launch(void* const* d_in, const int* in_sizes, int n_in,
                              void* d_out, int out_size, void* d_ws, size_t ws_size,
                              hipStream_t stream) {
    const float* in = (const float*)d_in[0];
    char* ws = (char*)d_ws;
    float*    score     = (float*)(ws + WS_SCORE);
    float*    cellBox   = (float*)(ws + WS_CELLBOX);
    float*    cellLabel = (float*)(ws + WS_CELLLAB);
    float*    keepOrig  = (float*)(ws + WS_KEEP);
    unsigned* rankPart  = (unsigned*)(ws + WS_RANKP);
    float* out = (float*)d_out;

    k_main<<<NBLK_K1, 64, 0, stream>>>(in, score, cellBox, cellLabel, keepOrig, rankPart);
    k_scatter<<<NCAND / 64, 64, 0, stream>>>(rankPart, score, cellBox, cellLabel,
                                             keepOrig, out);
}